// Round 8
// baseline (259.892 us; speedup 1.0000x reference)
//
#include <hip/hip_runtime.h>
#include <hip/hip_bf16.h>
#include <stdint.h>

#define BATCH 512
#define NN 32
#define T_IN 12
#define HID 64
#define HEADS 8
#define OUT_CH 9
#define EPB (NN*8)       // 256 edges per batch (before self loops)
#define ETOT (EPB+NN)    // 288 with self loops
#define F1 (HEADS*HID)   // 512

using u16 = unsigned short;
using u32 = unsigned int;
typedef _Float16 f16;
typedef _Float16 f16x2 __attribute__((ext_vector_type(2)));

__device__ __forceinline__ float bf2f(u16 u){ return __uint_as_float(((u32)u)<<16); }
__device__ __forceinline__ u16 f2bf(float f){
    u32 x = __float_as_uint(f);
    u32 r = (x + 0x7FFFu + ((x>>16)&1u))>>16;
    return (u16)r;
}
__device__ __forceinline__ u32 packf16(float a, float b){
    f16x2 p; p.x=(f16)a; p.y=(f16)b; return __builtin_bit_cast(u32,p);
}
__device__ __forceinline__ u16 f2h16(float a){ f16 h=(f16)a; return __builtin_bit_cast(u16,h); }
__device__ __forceinline__ float lof(u32 w){ return (float)__builtin_bit_cast(f16x2,w).x; }
__device__ __forceinline__ float hif(u32 w){ return (float)__builtin_bit_cast(f16x2,w).y; }
__device__ __forceinline__ float dot2(u32 a, u32 b, float c){
#if __has_builtin(__builtin_amdgcn_fdot2)
    return __builtin_amdgcn_fdot2(__builtin_bit_cast(f16x2,a), __builtin_bit_cast(f16x2,b), c, false);
#else
    return fmaf(lof(a),lof(b), fmaf(hif(a),hif(b), c));
#endif
}
__device__ __forceinline__ float elu1(float x){ return x > 0.f ? x : (__expf(x)-1.f); }
__device__ __forceinline__ float sigm(float x){ return 1.f/(1.f+__expf(-x)); }
__device__ __forceinline__ float tanh_(float x){ return 1.f - 2.f/(__expf(2.f*x)+1.f); }
// order-preserving float->u32 key for atomicMax
__device__ __forceinline__ u32 fenc(float v){
    u32 b=__float_as_uint(v);
    return (b&0x80000000u) ? ~b : (b|0x80000000u);
}
__device__ __forceinline__ float fdec(u32 k){
    return __uint_as_float((k&0x80000000u) ? (k&0x7FFFFFFFu) : ~k);
}

// ------------------------------------------------ dtype detection (fp32 vs bf16)
__global__ __launch_bounds__(256) void k_detect(const u32* __restrict__ xw, int* __restrict__ flag){
    __shared__ int cnt;
    if(threadIdx.x==0) cnt=0;
    __syncthreads();
    int c=0;
    for(int i=threadIdx.x;i<4096;i+=256){
        u32 w=xw[i];
        if(w & 0x7FFFFFFFu){
            u32 el=(w>>7)&0xFFu;
            if(el>=0x90u) c++;
        }
    }
    atomicAdd(&cnt,c);
    __syncthreads();
    if(threadIdx.x==0) *flag = (cnt>256) ? 1 : 0;   // 1 = fp32 inputs, 0 = bf16
}

// ------------------------------------------------ canonicalize inputs into ws (fp32)
struct CvtDesc {
    const void* src[16];
    void*       dst[16];
    int         n[16];
};

__global__ __launch_bounds__(256) void k_convert(CvtDesc d, const int* __restrict__ flag){
    const int seg = blockIdx.x;
    const int f = *flag;
    const void* s = d.src[seg];
    const int n = d.n[seg];
    const int stride = gridDim.y*256;
    float* o=(float*)d.dst[seg];
    for(int i=blockIdx.y*256+threadIdx.x;i<n;i+=stride)
        o[i] = f ? ((const float*)s)[i] : bf2f(((const u16*)s)[i]);
}

// W2 [512][64] -> interleaved fp16 W2i[(k>>3)*64+j][k&7]
__global__ __launch_bounds__(256) void k_w2i(const void* __restrict__ W2src, u16* __restrict__ W2i,
                                             const int* __restrict__ flag){
    int i = blockIdx.x*256+threadIdx.x;            // i = k*64+j
    int k=i>>6, j=i&63;
    float v = (*flag)? ((const float*)W2src)[i] : bf2f(((const u16*)W2src)[i]);
    W2i[ (((size_t)(k>>3)*64 + j)<<3) + (k&7) ] = f2h16(v);
}

// GRU weights -> packed fp16 [4 matrices][192 rows][32 u32 (K=64, Wi1 zero-padded)]
__global__ __launch_bounds__(256) void k_wpk(
    const void* __restrict__ Wi1, const void* __restrict__ Wh1,
    const void* __restrict__ Wi2, const void* __restrict__ Wh2,
    u32* __restrict__ wpk, const int* __restrict__ flag)
{
    int w = blockIdx.x*256+threadIdx.x;   // 0..24575
    int m = w/6144;
    int rem = w - m*6144;
    int row = rem>>5, kw = rem&31;
    const void* s = (m==0)?Wi1 : (m==1)?Wh1 : (m==2)?Wi2 : Wh2;
    int K = (m==0)?32:64;
    int f=*flag;
    int k0=2*kw, k1=k0+1;
    float v0=0.f, v1=0.f;
    if(k0<K) v0 = f? ((const float*)s)[row*K+k0] : bf2f(((const u16*)s)[row*K+k0]);
    if(k1<K) v1 = f? ((const float*)s)[row*K+k1] : bf2f(((const u16*)s)[row*K+k1]);
    wpk[w]=packf16(v0,v1);
}

// ---------------------------------------------------------------- GAT layer 1
__global__ __launch_bounds__(256,2) void k_gat1(
    const float* __restrict__ x, const int* __restrict__ ei,
    const float* __restrict__ W1, const float* __restrict__ a_s, const float* __restrict__ a_d,
    const float* __restrict__ b1, u32* __restrict__ h1g)
{
    const int b = blockIdx.x, t = threadIdx.x;
    __shared__ __align__(16) float s_x[NN][12];
    __shared__ float s_W1[T_IN*F1];
    __shared__ __align__(16) u16 s_h[NN][520];     // fp16, row pad 8 (16B-aligned rows)
    __shared__ u32 s_aspk[HEADS*32], s_adpk[HEADS*32];
    __shared__ float s_es[NN][HEADS], s_ed[NN][HEADS];
    __shared__ unsigned char s_src[ETOT], s_dst[ETOT];
    __shared__ float s_al[ETOT][HEADS];
    __shared__ u32 s_mx[NN*HEADS];
    __shared__ float s_sm[NN*HEADS], s_inv[NN*HEADS];
    __shared__ int s_cnt[NN], s_off[NN], s_fil[NN];
    __shared__ short s_lst[ETOT];

    for(int i=t;i<NN*T_IN;i+=256) s_x[i/12][i%12] = x[b*NN*T_IN + i];
    for(int i=t;i<T_IN*F1;i+=256) s_W1[i]=W1[i];
    s_aspk[t]=packf16(a_s[2*t],a_s[2*t+1]);
    s_adpk[t]=packf16(a_d[2*t],a_d[2*t+1]);
    s_mx[t]=0u; s_sm[t]=0.f;
    if(t<EPB){
        s_src[t] = (unsigned char)(ei[b*EPB+t] - b*NN);
        s_dst[t] = (unsigned char)(ei[(size_t)BATCH*EPB + b*EPB+t] - b*NN);
    }
    if(t<NN){ s_src[EPB+t]=s_dst[EPB+t]=(unsigned char)t; s_cnt[t]=0; s_fil[t]=0; }
    __syncthreads();

    // h = x @ W1 (pre-bias) -> LDS fp16 ; thread t owns columns t and t+256
    {
        float w0[12], w1[12];
        #pragma unroll
        for(int k=0;k<12;k++){ w0[k]=s_W1[k*F1+t]; w1[k]=s_W1[k*F1+t+256]; }
        for(int n=0;n<NN;n++){
            float xr[12];
            const float4* xp=(const float4*)s_x[n];
            *(float4*)&xr[0]=xp[0]; *(float4*)&xr[4]=xp[1]; *(float4*)&xr[8]=xp[2];
            float A=0.f,B=0.f;
            #pragma unroll
            for(int k=0;k<12;k++){ A=fmaf(xr[k],w0[k],A); B=fmaf(xr[k],w1[k],B); }
            s_h[n][t]=f2h16(A); s_h[n][t+256]=f2h16(B);
        }
    }
    for(int e=t;e<ETOT;e+=256) atomicAdd(&s_cnt[s_dst[e]],1);
    __syncthreads();

    // es/ed per (node, head) via fp16 dot2
    {
        int n=t&31, hd=t>>5;
        const uint4* hp=(const uint4*)((const u16*)s_h[n] + hd*64);
        u32 hw[32];
        #pragma unroll
        for(int q=0;q<8;q++) *(uint4*)&hw[q*4]=hp[q];
        float e1=0.f,e2=0.f;
        #pragma unroll
        for(int k=0;k<32;k++){ e1=dot2(hw[k],s_aspk[hd*32+k],e1); e2=dot2(hw[k],s_adpk[hd*32+k],e2); }
        s_es[n][hd]=e1; s_ed[n][hd]=e2;
    }
    if(t==0){ int o=0; for(int i=0;i<NN;i++){ s_off[i]=o; o+=s_cnt[i]; } }
    __syncthreads();

    // CSR fill (parallel) + edge-parallel logits + atomicMax
    for(int e=t;e<ETOT;e+=256){
        int d=s_dst[e]; int p=atomicAdd(&s_fil[d],1); s_lst[s_off[d]+p]=(short)e;
    }
    for(int i=t;i<ETOT*HEADS;i+=256){
        int e=i>>3, hd=i&7;
        int sr=s_src[e], d=s_dst[e];
        float v = s_es[sr][hd]+s_ed[d][hd];
        v = v>0.f? v : 0.2f*v;
        s_al[e][hd]=v;
        atomicMax(&s_mx[d*8+hd], fenc(v));
    }
    __syncthreads();

    // edge-parallel exp + sum
    for(int i=t;i<ETOT*HEADS;i+=256){
        int e=i>>3, hd=i&7;
        int d=s_dst[e];
        float p=__expf(s_al[e][hd]-fdec(s_mx[d*8+hd]));
        s_al[e][hd]=p;
        atomicAdd(&s_sm[d*8+hd], p);
    }
    __syncthreads();
    s_inv[t]=1.f/(s_sm[t]+1e-16f);
    __syncthreads();

    // aggregate (unscaled p), then scale by inv in epilogue; 2 column-chunks of 32
    {
        int d=t&31, hd=t>>5;
        int o=s_off[d], cnt=s_cnt[d];
        float inv=s_inv[d*8+hd];
        size_t obase = ((size_t)(b*NN+d))*256 + hd*32;
        #pragma unroll
        for(int ch=0;ch<2;ch++){
            float acc[32];
            #pragma unroll
            for(int i=0;i<32;i++) acc[i]=0.f;
            for(int i=0;i<cnt;i++){
                int e=s_lst[o+i]; float a=s_al[e][hd]; int sr=s_src[e];
                const uint4* hp=(const uint4*)((const u16*)s_h[sr] + hd*64 + ch*32);
                u32 pw[16];
                *(uint4*)&pw[0]=hp[0]; *(uint4*)&pw[4]=hp[1];
                *(uint4*)&pw[8]=hp[2]; *(uint4*)&pw[12]=hp[3];
                #pragma unroll
                for(int q=0;q<16;q++){ acc[2*q]+=a*lof(pw[q]); acc[2*q+1]+=a*hif(pw[q]); }
            }
            u32* op = h1g + obase + ch*16;
            #pragma unroll
            for(int j=0;j<16;j++){
                float v0=elu1(acc[2*j]*inv   + b1[hd*64+ch*32+2*j]);
                float v1=elu1(acc[2*j+1]*inv + b1[hd*64+ch*32+2*j+1]);
                op[j]=packf16(v0,v1);
            }
        }
    }
}

// --------------------------------------------- GAT layer 2 + LayerNorm (+transpose)
__global__ __launch_bounds__(256,2) void k_gat2ln(
    const u32* __restrict__ h1g, const int* __restrict__ ei,
    const uint4* __restrict__ W2i, const float* __restrict__ a_s2, const float* __restrict__ a_d2,
    const float* __restrict__ b2, const float* __restrict__ gam, const float* __restrict__ bet,
    float* __restrict__ hlng)
{
    const int b=blockIdx.x, t=threadIdx.x;
    __shared__ __align__(16) u32 s_h1[NN*260];   // fp16-packed rows, padded to 260 u32
    __shared__ float s_h2[NN][HID];
    __shared__ float s_es[NN], s_ed[NN];
    __shared__ unsigned char s_src[ETOT], s_dst[ETOT];
    __shared__ float s_al[ETOT];
    __shared__ u32 s_mx[NN];
    __shared__ float s_sm[NN], s_inv[NN];
    __shared__ int s_cnt[NN], s_off[NN], s_fil[NN];
    __shared__ short s_lst[ETOT];

    { const u32* g = h1g + (size_t)b*8192;
      for(int w=t; w<8192; w+=256){ int n=w>>8, c=w&255; s_h1[n*260+c]=g[w]; } }
    if(t<EPB){
        s_src[t]=(unsigned char)(ei[b*EPB+t]-b*NN);
        s_dst[t]=(unsigned char)(ei[(size_t)BATCH*EPB+b*EPB+t]-b*NN);
    }
    if(t<NN){ s_src[EPB+t]=s_dst[EPB+t]=(unsigned char)t;
              s_cnt[t]=0; s_fil[t]=0; s_mx[t]=0u; s_sm[t]=0.f; }
    __syncthreads();

    for(int e=t;e<ETOT;e+=256) atomicAdd(&s_cnt[s_dst[e]],1);
    // GEMM h2 = h1 @ W2 : 4 rows x 2 cols per thread (halves W2i L2 traffic)
    {
        int n0=(t>>5)<<2, j0=(t&31)<<1;
        const u32* r0=&s_h1[(n0+0)*260];
        const u32* r1=&s_h1[(n0+1)*260];
        const u32* r2=&s_h1[(n0+2)*260];
        const u32* r3=&s_h1[(n0+3)*260];
        float a00=0,a01=0,a10=0,a11=0,a20=0,a21=0,a30=0,a31=0;
        for(int kb=0;kb<64;kb++){
            uint4 A0=*(const uint4*)&r0[kb*4];
            uint4 A1=*(const uint4*)&r1[kb*4];
            uint4 A2=*(const uint4*)&r2[kb*4];
            uint4 A3=*(const uint4*)&r3[kb*4];
            const uint4* wp=&W2i[kb*64+j0];
            uint4 w0=wp[0], w1=wp[1];
            a00=dot2(A0.x,w0.x,a00); a00=dot2(A0.y,w0.y,a00); a00=dot2(A0.z,w0.z,a00); a00=dot2(A0.w,w0.w,a00);
            a01=dot2(A0.x,w1.x,a01); a01=dot2(A0.y,w1.y,a01); a01=dot2(A0.z,w1.z,a01); a01=dot2(A0.w,w1.w,a01);
            a10=dot2(A1.x,w0.x,a10); a10=dot2(A1.y,w0.y,a10); a10=dot2(A1.z,w0.z,a10); a10=dot2(A1.w,w0.w,a10);
            a11=dot2(A1.x,w1.x,a11); a11=dot2(A1.y,w1.y,a11); a11=dot2(A1.z,w1.z,a11); a11=dot2(A1.w,w1.w,a11);
            a20=dot2(A2.x,w0.x,a20); a20=dot2(A2.y,w0.y,a20); a20=dot2(A2.z,w0.z,a20); a20=dot2(A2.w,w0.w,a20);
            a21=dot2(A2.x,w1.x,a21); a21=dot2(A2.y,w1.y,a21); a21=dot2(A2.z,w1.z,a21); a21=dot2(A2.w,w1.w,a21);
            a30=dot2(A3.x,w0.x,a30); a30=dot2(A3.y,w0.y,a30); a30=dot2(A3.z,w0.z,a30); a30=dot2(A3.w,w0.w,a30);
            a31=dot2(A3.x,w1.x,a31); a31=dot2(A3.y,w1.y,a31); a31=dot2(A3.z,w1.z,a31); a31=dot2(A3.w,w1.w,a31);
        }
        s_h2[n0+0][j0]=a00; s_h2[n0+0][j0+1]=a01;
        s_h2[n0+1][j0]=a10; s_h2[n0+1][j0+1]=a11;
        s_h2[n0+2][j0]=a20; s_h2[n0+2][j0+1]=a21;
        s_h2[n0+3][j0]=a30; s_h2[n0+3][j0+1]=a31;
    }
    __syncthreads();

    // es/ed (single head) via 8-lane shuffle reduce
    {
        int n=t>>3, g=t&7;
        float e1=0,e2=0;
        #pragma unroll
        for(int cc=0; cc<8; cc++){
            float hv = s_h2[n][g*8+cc];
            e1 += hv*a_s2[g*8+cc];
            e2 += hv*a_d2[g*8+cc];
        }
        #pragma unroll
        for(int m=1;m<8;m<<=1){ e1 += __shfl_xor(e1,m,64); e2 += __shfl_xor(e2,m,64); }
        if(g==0){ s_es[n]=e1; s_ed[n]=e2; }
    }
    if(t==0){ int o=0; for(int i=0;i<NN;i++){ s_off[i]=o; o+=s_cnt[i]; } }
    __syncthreads();

    // CSR fill + edge-parallel logits + atomicMax
    for(int e=t;e<ETOT;e+=256){
        int d=s_dst[e]; int p=atomicAdd(&s_fil[d],1); s_lst[s_off[d]+p]=(short)e;
    }
    for(int e=t;e<ETOT;e+=256){
        int d=s_dst[e];
        float v = s_es[s_src[e]] + s_ed[d];
        v = v>0.f? v:0.2f*v;
        s_al[e]=v;
        atomicMax(&s_mx[d], fenc(v));
    }
    __syncthreads();

    for(int e=t;e<ETOT;e+=256){
        int d=s_dst[e];
        float p=__expf(s_al[e]-fdec(s_mx[d]));
        s_al[e]=p;
        atomicAdd(&s_sm[d], p);
    }
    __syncthreads();
    if(t<NN) s_inv[t]=1.f/(s_sm[t]+1e-16f);
    __syncthreads();

    // aggregate + scale + b2 + ELU + LayerNorm + transposed store [b][c][n]
    {
        int n=t>>3, g=t&7;
        float acc[8];
        #pragma unroll
        for(int i=0;i<8;i++) acc[i]=0;
        int o=s_off[n], cnt=s_cnt[n];
        float inv=s_inv[n];
        for(int i=0;i<cnt;i++){
            int e=s_lst[o+i]; float a=s_al[e]; int sr=s_src[e];
            const float4* hp=(const float4*)&s_h2[sr][g*8];
            float4 v0=hp[0], v1=hp[1];
            acc[0]+=a*v0.x; acc[1]+=a*v0.y; acc[2]+=a*v0.z; acc[3]+=a*v0.w;
            acc[4]+=a*v1.x; acc[5]+=a*v1.y; acc[6]+=a*v1.z; acc[7]+=a*v1.w;
        }
        float sum=0,sq=0;
        #pragma unroll
        for(int i=0;i<8;i++){
            float v = elu1(acc[i]*inv + b2[g*8+i]);
            acc[i]=v; sum+=v; sq+=v*v;
        }
        #pragma unroll
        for(int m=1;m<8;m<<=1){ sum+=__shfl_xor(sum,m,64); sq+=__shfl_xor(sq,m,64); }
        float mu = sum*(1.f/64.f);
        float var = sq*(1.f/64.f) - mu*mu;
        float rs = rsqrtf(var + 1e-5f);
        float* outp = hlng + (size_t)b*HID*NN;
        #pragma unroll
        for(int i=0;i<8;i++){
            int c=g*8+i;
            float v=(acc[i]-mu)*rs*gam[c] + bet[c];
            outp[c*NN + n] = v;
        }
    }
}

// --------------------------------- Fused GRU1+GRU2+FC, 4-way k-split, pinned weights
// 512 threads = 8 waves. Waves 0-3: GRU1 units [w*16..w*16+15]; waves 4-7: GRU2.
// Lane = kq*16 + uu. Weights pinned in VGPRs via opaque asm (defeats load sinking).
__global__ __launch_bounds__(512,1) void k_gruf(
    const float* __restrict__ hlng, const u32* __restrict__ wpk,
    const float* __restrict__ bi1, const float* __restrict__ bh1,
    const float* __restrict__ bi2, const float* __restrict__ bh2,
    const float* __restrict__ Wf, const float* __restrict__ bfv,
    void* __restrict__ outp, const int* __restrict__ flag)
{
    const int b=blockIdx.x, t=threadIdx.x;
    const int wave=t>>6, lane=t&63;
    const int layer=wave>>2;          // 0 = GRU1 waves, 1 = GRU2 waves
    const int uu=lane&15, kq=lane>>4; // unit-within-wave, k-quarter
    const int u=(wave&3)*16+uu;       // hidden unit 0..63

    __shared__ __align__(16) u32 s_x1[64][32];  // GRU1 input fp16, K zero-padded to 64
    __shared__ __align__(16) u32 s_h1[2][32];   // y1/h1 double buffer (64 f16)
    __shared__ __align__(16) u32 s_h2[2][32];   // h2 double buffer
    __shared__ float s_h2f[64];                 // final h2 fp32

    {   const float2* g=(const float2*)(hlng + (size_t)b*2048);
        for(int w=t;w<2048;w+=512){
            int step=w>>5, j=w&31;
            u32 v=0u;
            if(j<16){ float2 f=g[step*16+j]; v=packf16(f.x,f.y); }
            s_x1[step][j]=v;
        }
    }
    if(t<32){ s_h1[0][t]=0u; s_h1[1][t]=0u; s_h2[0][t]=0u; s_h2[1][t]=0u; }

    // straight-line weight init: 12 uint4 loads
    const u32* wi = wpk + (size_t)(layer*2+0)*6144 + kq*8;
    const u32* wh = wpk + (size_t)(layer*2+1)*6144 + kq*8;
    u32 wiR[8],wiZ[8],wiN[8],whR[8],whZ[8],whN[8];
    *(uint4*)&wiR[0]=*(const uint4*)&wi[(u     )*32];
    *(uint4*)&wiR[4]=*(const uint4*)&wi[(u     )*32+4];
    *(uint4*)&wiZ[0]=*(const uint4*)&wi[(64+u  )*32];
    *(uint4*)&wiZ[4]=*(const uint4*)&wi[(64+u  )*32+4];
    *(uint4*)&wiN[0]=*(const uint4*)&wi[(128+u )*32];
    *(uint4*)&wiN[4]=*(const uint4*)&wi[(128+u )*32+4];
    *(uint4*)&whR[0]=*(const uint4*)&wh[(u     )*32];
    *(uint4*)&whR[4]=*(const uint4*)&wh[(u     )*32+4];
    *(uint4*)&whZ[0]=*(const uint4*)&wh[(64+u  )*32];
    *(uint4*)&whZ[4]=*(const uint4*)&wh[(64+u  )*32+4];
    *(uint4*)&whN[0]=*(const uint4*)&wh[(128+u )*32];
    *(uint4*)&whN[4]=*(const uint4*)&wh[(128+u )*32+4];

    const float* bi = layer? bi2:bi1;
    const float* bh = layer? bh2:bh1;
    float br=bi[u]+bh[u], bz=bi[64+u]+bh[64+u], bxn=bi[128+u], bhn=bh[128+u];

    // PIN: opaque asm use forces all 48 weight words + biases to stay VGPR-resident
    // across the loop (compiler cannot rematerialize/sink across the asm).
    #pragma unroll
    for(int k=0;k<8;k++){
        asm volatile("" : "+v"(wiR[k]),"+v"(wiZ[k]),"+v"(wiN[k]),
                          "+v"(whR[k]),"+v"(whZ[k]),"+v"(whN[k]));
    }
    asm volatile("" : "+v"(br),"+v"(bz),"+v"(bxn),"+v"(bhn));

    float h=0.f;
    __syncthreads();

    for(int it=0; it<=64; ++it){
        const int pb=(it-1)&1, cb=it&1;
        const bool act = layer ? (it>=1) : (it<64);
        if(act){
            u32 xw[8], hw[8];
            const uint4* xp = layer ? (const uint4*)&s_h1[pb][kq*8]
                                    : (const uint4*)&s_x1[it][kq*8];
            *(uint4*)&xw[0]=xp[0]; *(uint4*)&xw[4]=xp[1];
            const uint4* hp = layer ? (const uint4*)&s_h2[pb][kq*8]
                                    : (const uint4*)&s_h1[pb][kq*8];
            *(uint4*)&hw[0]=hp[0]; *(uint4*)&hw[4]=hp[1];
            float pr=0.f,pz=0.f,pxn=0.f,phn=0.f;
            #pragma unroll
            for(int k=0;k<8;k++){
                pr=dot2(xw[k],wiR[k],pr); pz=dot2(xw[k],wiZ[k],pz); pxn=dot2(xw[k],wiN[k],pxn);
                pr=dot2(hw[k],whR[k],pr); pz=dot2(hw[k],whZ[k],pz); phn=dot2(hw[k],whN[k],phn);
            }
            // combine 4 k-quarters (all lanes end with full sums)
            pr +=__shfl_xor(pr ,16,64); pz +=__shfl_xor(pz ,16,64);
            pxn+=__shfl_xor(pxn,16,64); phn+=__shfl_xor(phn,16,64);
            pr +=__shfl_xor(pr ,32,64); pz +=__shfl_xor(pz ,32,64);
            pxn+=__shfl_xor(pxn,32,64); phn+=__shfl_xor(phn,32,64);
            float r=sigm(pr+br), z=sigm(pz+bz);
            float n=tanh_(pxn+bxn + r*(phn+bhn));
            h=(1.f-z)*n + z*h;
            if(kq==0){
                u16 hv=f2h16(h);
                if(layer==0) ((u16*)s_h1[cb])[u]=hv;
                else { ((u16*)s_h2[cb])[u]=hv; if(it==64) s_h2f[u]=h; }
            }
        }
        __syncthreads();
    }

    if(t<OUT_CH){
        float acc=bfv[t];
        const float4* wp=(const float4*)(Wf + t*64);
        const float4* hp=(const float4*)s_h2f;
        #pragma unroll
        for(int k=0;k<16;k++){
            float4 w=wp[k], v=hp[k];
            acc += w.x*v.x + w.y*v.y + w.z*v.z + w.w*v.w;
        }
        if(*flag) ((float*)outp)[b*OUT_CH+t]=acc;
        else      ((u16*)outp)[b*OUT_CH+t]=f2bf(acc);
    }
}

extern "C" void kernel_launch(void* const* d_in, const int* in_sizes, int n_in,
                              void* d_out, int out_size, void* d_ws, size_t ws_size,
                              hipStream_t stream)
{
    char* ws=(char*)d_ws;
    int* flag = (int*)ws;
    float* cf = (float*)(ws + 256);
    float* c_x   = cf; cf+=196608;
    float* c_W1  = cf; cf+=6144;
    float* c_as1 = cf; cf+=512;
    float* c_ad1 = cf; cf+=512;
    float* c_b1  = cf; cf+=512;
    float* c_as2 = cf; cf+=64;
    float* c_ad2 = cf; cf+=64;
    float* c_b2  = cf; cf+=64;
    float* c_gam = cf; cf+=64;
    float* c_bet = cf; cf+=64;
    float* c_bi1 = cf; cf+=192;
    float* c_bh1 = cf; cf+=192;
    float* c_bi2 = cf; cf+=192;
    float* c_bh2 = cf; cf+=192;
    float* c_Wf  = cf; cf+=576;
    float* c_bf  = cf; cf+=9;
    uintptr_t p = ((uintptr_t)cf + 255) & ~(uintptr_t)255;
    u16* c_W2i = (u16*)p;                        // 32768 f16 = 64 KB (interleaved)
    p = (p + 32768*2 + 255) & ~(uintptr_t)255;
    u32* wpk = (u32*)p;                          // 4*192*32 u32 = 96 KB (packed GRU weights)
    p = (p + 24576*4 + 255) & ~(uintptr_t)255;
    u32* h1g = (u32*)p;                          // 512*32*256 u32 = 16.78 MB (fp16-packed)
    p = (p + (size_t)BATCH*NN*256*4 + 255) & ~(uintptr_t)255;
    float* hlng = (float*)p;                     // 512*64*32 f32 = 4.19 MB

    const int* ei = (const int*)d_in[1];

    CvtDesc d;
    const int srcIdx[16] = {0,2,3,4,5,7,8,9,10,11,14,15,18,19,20,21};
    void* dsts[16] = {c_x,c_W1,c_as1,c_ad1,c_b1,c_as2,c_ad2,c_b2,c_gam,c_bet,
                      c_bi1,c_bh1,c_bi2,c_bh2,c_Wf,c_bf};
    const int ns[16] = {196608,6144,512,512,512,64,64,64,64,64,
                        192,192,192,192,576,9};
    for(int i=0;i<16;i++){ d.src[i]=d_in[srcIdx[i]]; d.dst[i]=dsts[i]; d.n[i]=ns[i]; }

    k_detect <<<dim3(1),dim3(256),0,stream>>>((const u32*)d_in[0], flag);
    k_convert<<<dim3(16,8),dim3(256),0,stream>>>(d, flag);
    k_w2i    <<<dim3(128),dim3(256),0,stream>>>(d_in[6], c_W2i, flag);
    k_wpk    <<<dim3(96),dim3(256),0,stream>>>(d_in[12],d_in[13],d_in[16],d_in[17], wpk, flag);
    k_gat1   <<<dim3(BATCH),dim3(256),0,stream>>>(c_x,ei,c_W1,c_as1,c_ad1,c_b1,h1g);
    k_gat2ln <<<dim3(BATCH),dim3(256),0,stream>>>(h1g,ei,(const uint4*)c_W2i,c_as2,c_ad2,c_b2,c_gam,c_bet,hlng);
    k_gruf   <<<dim3(BATCH),dim3(512),0,stream>>>(hlng,wpk,c_bi1,c_bh1,c_bi2,c_bh2,c_Wf,c_bf,d_out,flag);
}

// Round 9
// 253.886 us; speedup vs baseline: 1.0237x; 1.0237x over previous
//
#include <hip/hip_runtime.h>
#include <hip/hip_bf16.h>
#include <stdint.h>

#define BATCH 512
#define NN 32
#define T_IN 12
#define HID 64
#define HEADS 8
#define OUT_CH 9
#define EPB (NN*8)       // 256 edges per batch (before self loops)
#define ETOT (EPB+NN)    // 288 with self loops
#define F1 (HEADS*HID)   // 512

using u16 = unsigned short;
using u32 = unsigned int;
typedef _Float16 f16;
typedef _Float16 f16x2 __attribute__((ext_vector_type(2)));
typedef u32 v4u __attribute__((ext_vector_type(4)));

__device__ __forceinline__ float bf2f(u16 u){ return __uint_as_float(((u32)u)<<16); }
__device__ __forceinline__ u16 f2bf(float f){
    u32 x = __float_as_uint(f);
    u32 r = (x + 0x7FFFu + ((x>>16)&1u))>>16;
    return (u16)r;
}
__device__ __forceinline__ u32 packf16(float a, float b){
    f16x2 p; p.x=(f16)a; p.y=(f16)b; return __builtin_bit_cast(u32,p);
}
__device__ __forceinline__ u16 f2h16(float a){ f16 h=(f16)a; return __builtin_bit_cast(u16,h); }
__device__ __forceinline__ float lof(u32 w){ return (float)__builtin_bit_cast(f16x2,w).x; }
__device__ __forceinline__ float hif(u32 w){ return (float)__builtin_bit_cast(f16x2,w).y; }
__device__ __forceinline__ float dot2(u32 a, u32 b, float c){
#if __has_builtin(__builtin_amdgcn_fdot2)
    return __builtin_amdgcn_fdot2(__builtin_bit_cast(f16x2,a), __builtin_bit_cast(f16x2,b), c, false);
#else
    return fmaf(lof(a),lof(b), fmaf(hif(a),hif(b), c));
#endif
}
__device__ __forceinline__ float elu1(float x){ return x > 0.f ? x : (__expf(x)-1.f); }
__device__ __forceinline__ float sigm(float x){ return 1.f/(1.f+__expf(-x)); }
__device__ __forceinline__ float tanh_(float x){ return 1.f - 2.f/(__expf(2.f*x)+1.f); }
__device__ __forceinline__ u32 fenc(float v){
    u32 b=__float_as_uint(v);
    return (b&0x80000000u) ? ~b : (b|0x80000000u);
}
__device__ __forceinline__ float fdec(u32 k){
    return __uint_as_float((k&0x80000000u) ? (k&0x7FFFFFFFu) : ~k);
}

#define DOT4(acc,A,W) do{ acc=dot2(A.x,W.x,acc); acc=dot2(A.y,W.y,acc); \
                          acc=dot2(A.z,W.z,acc); acc=dot2(A.w,W.w,acc); }while(0)
#define DOT8(acc,A0,A1,W0,W1) do{ DOT4(acc,A0,W0); DOT4(acc,A1,W1); }while(0)

// ------------------------------------------------ dtype detection (fp32 vs bf16)
__global__ __launch_bounds__(256) void k_detect(const u32* __restrict__ xw, int* __restrict__ flag){
    __shared__ int cnt;
    if(threadIdx.x==0) cnt=0;
    __syncthreads();
    int c=0;
    for(int i=threadIdx.x;i<4096;i+=256){
        u32 w=xw[i];
        if(w & 0x7FFFFFFFu){
            u32 el=(w>>7)&0xFFu;
            if(el>=0x90u) c++;
        }
    }
    atomicAdd(&cnt,c);
    __syncthreads();
    if(threadIdx.x==0) *flag = (cnt>256) ? 1 : 0;   // 1 = fp32 inputs, 0 = bf16
}

// ------------------------------------------------ canonicalize inputs into ws (fp32)
struct CvtDesc {
    const void* src[16];
    void*       dst[16];
    int         n[16];
};

__global__ __launch_bounds__(256) void k_convert(CvtDesc d, const int* __restrict__ flag){
    const int seg = blockIdx.x;
    const int f = *flag;
    const void* s = d.src[seg];
    const int n = d.n[seg];
    const int stride = gridDim.y*256;
    float* o=(float*)d.dst[seg];
    for(int i=blockIdx.y*256+threadIdx.x;i<n;i+=stride)
        o[i] = f ? ((const float*)s)[i] : bf2f(((const u16*)s)[i]);
}

// W2 [512][64] -> interleaved fp16 W2i[(k>>3)*64+j][k&7]
__global__ __launch_bounds__(256) void k_w2i(const void* __restrict__ W2src, u16* __restrict__ W2i,
                                             const int* __restrict__ flag){
    int i = blockIdx.x*256+threadIdx.x;            // i = k*64+j
    int k=i>>6, j=i&63;
    float v = (*flag)? ((const float*)W2src)[i] : bf2f(((const u16*)W2src)[i]);
    W2i[ (((size_t)(k>>3)*64 + j)<<3) + (k&7) ] = f2h16(v);
}

// GRU weights -> packed fp16 [4 matrices][192 rows][32 u32 (K=64, Wi1 zero-padded)]
__global__ __launch_bounds__(256) void k_wpk(
    const void* __restrict__ Wi1, const void* __restrict__ Wh1,
    const void* __restrict__ Wi2, const void* __restrict__ Wh2,
    u32* __restrict__ wpk, const int* __restrict__ flag)
{
    int w = blockIdx.x*256+threadIdx.x;   // 0..24575
    int m = w/6144;
    int rem = w - m*6144;
    int row = rem>>5, kw = rem&31;
    const void* s = (m==0)?Wi1 : (m==1)?Wh1 : (m==2)?Wi2 : Wh2;
    int K = (m==0)?32:64;
    int f=*flag;
    int k0=2*kw, k1=k0+1;
    float v0=0.f, v1=0.f;
    if(k0<K) v0 = f? ((const float*)s)[row*K+k0] : bf2f(((const u16*)s)[row*K+k0]);
    if(k1<K) v1 = f? ((const float*)s)[row*K+k1] : bf2f(((const u16*)s)[row*K+k1]);
    wpk[w]=packf16(v0,v1);
}

// ---------------------------------------------------------------- GAT layer 1
__global__ __launch_bounds__(256,2) void k_gat1(
    const float* __restrict__ x, const int* __restrict__ ei,
    const float* __restrict__ W1, const float* __restrict__ a_s, const float* __restrict__ a_d,
    const float* __restrict__ b1, u32* __restrict__ h1g)
{
    const int b = blockIdx.x, t = threadIdx.x;
    __shared__ __align__(16) float s_x[NN][12];
    __shared__ float s_W1[T_IN*F1];
    __shared__ __align__(16) u16 s_h[NN][520];     // fp16, row pad 8 (rows 1040B = 16B-aligned)
    __shared__ __align__(16) u32 s_aspk[HEADS*32], s_adpk[HEADS*32];
    __shared__ float s_es[NN][HEADS], s_ed[NN][HEADS];
    __shared__ unsigned char s_src[ETOT], s_dst[ETOT];
    __shared__ float s_al[ETOT][HEADS];
    __shared__ u32 s_mx[NN*HEADS];
    __shared__ float s_sm[NN*HEADS], s_inv[NN*HEADS];
    __shared__ int s_cnt[NN], s_off[NN], s_fil[NN];
    __shared__ short s_lst[ETOT];

    for(int i=t;i<NN*T_IN;i+=256) s_x[i/12][i%12] = x[b*NN*T_IN + i];
    for(int i=t;i<T_IN*F1;i+=256) s_W1[i]=W1[i];
    s_aspk[t]=packf16(a_s[2*t],a_s[2*t+1]);
    s_adpk[t]=packf16(a_d[2*t],a_d[2*t+1]);
    s_mx[t]=0u; s_sm[t]=0.f;
    if(t<EPB){
        s_src[t] = (unsigned char)(ei[b*EPB+t] - b*NN);
        s_dst[t] = (unsigned char)(ei[(size_t)BATCH*EPB + b*EPB+t] - b*NN);
    }
    if(t<NN){ s_src[EPB+t]=s_dst[EPB+t]=(unsigned char)t; s_cnt[t]=0; s_fil[t]=0; }
    __syncthreads();

    // h = x @ W1 (pre-bias) -> LDS fp16 ; thread t owns columns t and t+256
    {
        float w0[12], w1[12];
        #pragma unroll
        for(int k=0;k<12;k++){ w0[k]=s_W1[k*F1+t]; w1[k]=s_W1[k*F1+t+256]; }
        for(int n=0;n<NN;n++){
            const float4* xp=(const float4*)s_x[n];
            float4 xa=xp[0], xb=xp[1], xc=xp[2];
            float A=0.f,B=0.f;
            A=fmaf(xa.x,w0[0],A); A=fmaf(xa.y,w0[1],A); A=fmaf(xa.z,w0[2],A); A=fmaf(xa.w,w0[3],A);
            A=fmaf(xb.x,w0[4],A); A=fmaf(xb.y,w0[5],A); A=fmaf(xb.z,w0[6],A); A=fmaf(xb.w,w0[7],A);
            A=fmaf(xc.x,w0[8],A); A=fmaf(xc.y,w0[9],A); A=fmaf(xc.z,w0[10],A); A=fmaf(xc.w,w0[11],A);
            B=fmaf(xa.x,w1[0],B); B=fmaf(xa.y,w1[1],B); B=fmaf(xa.z,w1[2],B); B=fmaf(xa.w,w1[3],B);
            B=fmaf(xb.x,w1[4],B); B=fmaf(xb.y,w1[5],B); B=fmaf(xb.z,w1[6],B); B=fmaf(xb.w,w1[7],B);
            B=fmaf(xc.x,w1[8],B); B=fmaf(xc.y,w1[9],B); B=fmaf(xc.z,w1[10],B); B=fmaf(xc.w,w1[11],B);
            s_h[n][t]=f2h16(A); s_h[n][t+256]=f2h16(B);
        }
    }
    for(int e=t;e<ETOT;e+=256) atomicAdd(&s_cnt[s_dst[e]],1);
    __syncthreads();

    // es/ed per (node, head) via fp16 dot2 — vector scalars, no local arrays
    {
        int n=t&31, hd=t>>5;
        const v4u* hp=(const v4u*)((const u16*)s_h[n] + hd*64);
        v4u h0=hp[0],h1=hp[1],h2=hp[2],h3=hp[3],h4=hp[4],h5=hp[5],h6=hp[6],h7=hp[7];
        const v4u* ap=(const v4u*)&s_aspk[hd*32];
        const v4u* dp=(const v4u*)&s_adpk[hd*32];
        float e1=0.f,e2=0.f;
        { v4u w=ap[0]; DOT4(e1,h0,w); w=ap[1]; DOT4(e1,h1,w); w=ap[2]; DOT4(e1,h2,w); w=ap[3]; DOT4(e1,h3,w);
          w=ap[4]; DOT4(e1,h4,w); w=ap[5]; DOT4(e1,h5,w); w=ap[6]; DOT4(e1,h6,w); w=ap[7]; DOT4(e1,h7,w); }
        { v4u w=dp[0]; DOT4(e2,h0,w); w=dp[1]; DOT4(e2,h1,w); w=dp[2]; DOT4(e2,h2,w); w=dp[3]; DOT4(e2,h3,w);
          w=dp[4]; DOT4(e2,h4,w); w=dp[5]; DOT4(e2,h5,w); w=dp[6]; DOT4(e2,h6,w); w=dp[7]; DOT4(e2,h7,w); }
        s_es[n][hd]=e1; s_ed[n][hd]=e2;
    }
    if(t==0){ int o=0; for(int i=0;i<NN;i++){ s_off[i]=o; o+=s_cnt[i]; } }
    __syncthreads();

    // CSR fill (parallel) + edge-parallel logits + atomicMax
    for(int e=t;e<ETOT;e+=256){
        int d=s_dst[e]; int p=atomicAdd(&s_fil[d],1); s_lst[s_off[d]+p]=(short)e;
    }
    for(int i=t;i<ETOT*HEADS;i+=256){
        int e=i>>3, hd=i&7;
        int sr=s_src[e], d=s_dst[e];
        float v = s_es[sr][hd]+s_ed[d][hd];
        v = v>0.f? v : 0.2f*v;
        s_al[e][hd]=v;
        atomicMax(&s_mx[d*8+hd], fenc(v));
    }
    __syncthreads();

    // edge-parallel exp + sum
    for(int i=t;i<ETOT*HEADS;i+=256){
        int e=i>>3, hd=i&7;
        int d=s_dst[e];
        float p=__expf(s_al[e][hd]-fdec(s_mx[d*8+hd]));
        s_al[e][hd]=p;
        atomicAdd(&s_sm[d*8+hd], p);
    }
    __syncthreads();
    s_inv[t]=1.f/(s_sm[t]+1e-16f);
    __syncthreads();

    // aggregate (unscaled p), scale by inv in epilogue; 2 column-chunks of 32
    {
        int d=t&31, hd=t>>5;
        int o=s_off[d], cnt=s_cnt[d];
        float inv=s_inv[d*8+hd];
        size_t obase = ((size_t)(b*NN+d))*256 + hd*32;
        #pragma unroll
        for(int ch=0;ch<2;ch++){
            float acc[32];
            #pragma unroll
            for(int i=0;i<32;i++) acc[i]=0.f;
            for(int i=0;i<cnt;i++){
                int e=s_lst[o+i]; float a=s_al[e][hd]; int sr=s_src[e];
                const v4u* hp=(const v4u*)((const u16*)s_h[sr] + hd*64 + ch*32);
                v4u p0=hp[0],p1=hp[1],p2=hp[2],p3=hp[3];
                #define ACC2(i,w) acc[2*(i)]+=a*lof(w); acc[2*(i)+1]+=a*hif(w);
                ACC2(0,p0.x) ACC2(1,p0.y) ACC2(2,p0.z) ACC2(3,p0.w)
                ACC2(4,p1.x) ACC2(5,p1.y) ACC2(6,p1.z) ACC2(7,p1.w)
                ACC2(8,p2.x) ACC2(9,p2.y) ACC2(10,p2.z) ACC2(11,p2.w)
                ACC2(12,p3.x) ACC2(13,p3.y) ACC2(14,p3.z) ACC2(15,p3.w)
                #undef ACC2
            }
            u32* op = h1g + obase + ch*16;
            #pragma unroll
            for(int j=0;j<16;j++){
                float v0=elu1(acc[2*j]*inv   + b1[hd*64+ch*32+2*j]);
                float v1=elu1(acc[2*j+1]*inv + b1[hd*64+ch*32+2*j+1]);
                op[j]=packf16(v0,v1);
            }
        }
    }
}

// --------------------------------------------- GAT layer 2 + LayerNorm (+transpose)
__global__ __launch_bounds__(256,2) void k_gat2ln(
    const u32* __restrict__ h1g, const int* __restrict__ ei,
    const uint4* __restrict__ W2i, const float* __restrict__ a_s2, const float* __restrict__ a_d2,
    const float* __restrict__ b2, const float* __restrict__ gam, const float* __restrict__ bet,
    float* __restrict__ hlng)
{
    const int b=blockIdx.x, t=threadIdx.x;
    __shared__ __align__(16) u32 s_h1[NN*260];   // fp16-packed rows, padded to 260 u32
    __shared__ float s_h2[NN][HID];
    __shared__ float s_es[NN], s_ed[NN];
    __shared__ unsigned char s_src[ETOT], s_dst[ETOT];
    __shared__ float s_al[ETOT];
    __shared__ u32 s_mx[NN];
    __shared__ float s_sm[NN], s_inv[NN];
    __shared__ int s_cnt[NN], s_off[NN], s_fil[NN];
    __shared__ short s_lst[ETOT];

    { const u32* g = h1g + (size_t)b*8192;
      for(int w=t; w<8192; w+=256){ int n=w>>8, c=w&255; s_h1[n*260+c]=g[w]; } }
    if(t<EPB){
        s_src[t]=(unsigned char)(ei[b*EPB+t]-b*NN);
        s_dst[t]=(unsigned char)(ei[(size_t)BATCH*EPB+b*EPB+t]-b*NN);
    }
    if(t<NN){ s_src[EPB+t]=s_dst[EPB+t]=(unsigned char)t;
              s_cnt[t]=0; s_fil[t]=0; s_mx[t]=0u; s_sm[t]=0.f; }
    __syncthreads();

    for(int e=t;e<ETOT;e+=256) atomicAdd(&s_cnt[s_dst[e]],1);
    // GEMM h2 = h1 @ W2 : 4 rows x 2 cols per thread
    {
        int n0=(t>>5)<<2, j0=(t&31)<<1;
        const u32* r0=&s_h1[(n0+0)*260];
        const u32* r1=&s_h1[(n0+1)*260];
        const u32* r2=&s_h1[(n0+2)*260];
        const u32* r3=&s_h1[(n0+3)*260];
        float a00=0,a01=0,a10=0,a11=0,a20=0,a21=0,a30=0,a31=0;
        for(int kb=0;kb<64;kb++){
            uint4 A0=*(const uint4*)&r0[kb*4];
            uint4 A1=*(const uint4*)&r1[kb*4];
            uint4 A2=*(const uint4*)&r2[kb*4];
            uint4 A3=*(const uint4*)&r3[kb*4];
            const uint4* wp=&W2i[kb*64+j0];
            uint4 w0=wp[0], w1=wp[1];
            a00=dot2(A0.x,w0.x,a00); a00=dot2(A0.y,w0.y,a00); a00=dot2(A0.z,w0.z,a00); a00=dot2(A0.w,w0.w,a00);
            a01=dot2(A0.x,w1.x,a01); a01=dot2(A0.y,w1.y,a01); a01=dot2(A0.z,w1.z,a01); a01=dot2(A0.w,w1.w,a01);
            a10=dot2(A1.x,w0.x,a10); a10=dot2(A1.y,w0.y,a10); a10=dot2(A1.z,w0.z,a10); a10=dot2(A1.w,w0.w,a10);
            a11=dot2(A1.x,w1.x,a11); a11=dot2(A1.y,w1.y,a11); a11=dot2(A1.z,w1.z,a11); a11=dot2(A1.w,w1.w,a11);
            a20=dot2(A2.x,w0.x,a20); a20=dot2(A2.y,w0.y,a20); a20=dot2(A2.z,w0.z,a20); a20=dot2(A2.w,w0.w,a20);
            a21=dot2(A2.x,w1.x,a21); a21=dot2(A2.y,w1.y,a21); a21=dot2(A2.z,w1.z,a21); a21=dot2(A2.w,w1.w,a21);
            a30=dot2(A3.x,w0.x,a30); a30=dot2(A3.y,w0.y,a30); a30=dot2(A3.z,w0.z,a30); a30=dot2(A3.w,w0.w,a30);
            a31=dot2(A3.x,w1.x,a31); a31=dot2(A3.y,w1.y,a31); a31=dot2(A3.z,w1.z,a31); a31=dot2(A3.w,w1.w,a31);
        }
        s_h2[n0+0][j0]=a00; s_h2[n0+0][j0+1]=a01;
        s_h2[n0+1][j0]=a10; s_h2[n0+1][j0+1]=a11;
        s_h2[n0+2][j0]=a20; s_h2[n0+2][j0+1]=a21;
        s_h2[n0+3][j0]=a30; s_h2[n0+3][j0+1]=a31;
    }
    __syncthreads();

    // es/ed (single head) via 8-lane shuffle reduce
    {
        int n=t>>3, g=t&7;
        float e1=0,e2=0;
        #pragma unroll
        for(int cc=0; cc<8; cc++){
            float hv = s_h2[n][g*8+cc];
            e1 += hv*a_s2[g*8+cc];
            e2 += hv*a_d2[g*8+cc];
        }
        #pragma unroll
        for(int m=1;m<8;m<<=1){ e1 += __shfl_xor(e1,m,64); e2 += __shfl_xor(e2,m,64); }
        if(g==0){ s_es[n]=e1; s_ed[n]=e2; }
    }
    if(t==0){ int o=0; for(int i=0;i<NN;i++){ s_off[i]=o; o+=s_cnt[i]; } }
    __syncthreads();

    // CSR fill + edge-parallel logits + atomicMax
    for(int e=t;e<ETOT;e+=256){
        int d=s_dst[e]; int p=atomicAdd(&s_fil[d],1); s_lst[s_off[d]+p]=(short)e;
    }
    for(int e=t;e<ETOT;e+=256){
        int d=s_dst[e];
        float v = s_es[s_src[e]] + s_ed[d];
        v = v>0.f? v:0.2f*v;
        s_al[e]=v;
        atomicMax(&s_mx[d], fenc(v));
    }
    __syncthreads();

    for(int e=t;e<ETOT;e+=256){
        int d=s_dst[e];
        float p=__expf(s_al[e]-fdec(s_mx[d]));
        s_al[e]=p;
        atomicAdd(&s_sm[d], p);
    }
    __syncthreads();
    if(t<NN) s_inv[t]=1.f/(s_sm[t]+1e-16f);
    __syncthreads();

    // aggregate + scale + b2 + ELU + LayerNorm + transposed store [b][c][n]
    {
        int n=t>>3, g=t&7;
        float acc[8];
        #pragma unroll
        for(int i=0;i<8;i++) acc[i]=0;
        int o=s_off[n], cnt=s_cnt[n];
        float inv=s_inv[n];
        for(int i=0;i<cnt;i++){
            int e=s_lst[o+i]; float a=s_al[e]; int sr=s_src[e];
            const float4* hp=(const float4*)&s_h2[sr][g*8];
            float4 v0=hp[0], v1=hp[1];
            acc[0]+=a*v0.x; acc[1]+=a*v0.y; acc[2]+=a*v0.z; acc[3]+=a*v0.w;
            acc[4]+=a*v1.x; acc[5]+=a*v1.y; acc[6]+=a*v1.z; acc[7]+=a*v1.w;
        }
        float sum=0,sq=0;
        #pragma unroll
        for(int i=0;i<8;i++){
            float v = elu1(acc[i]*inv + b2[g*8+i]);
            acc[i]=v; sum+=v; sq+=v*v;
        }
        #pragma unroll
        for(int m=1;m<8;m<<=1){ sum+=__shfl_xor(sum,m,64); sq+=__shfl_xor(sq,m,64); }
        float mu = sum*(1.f/64.f);
        float var = sq*(1.f/64.f) - mu*mu;
        float rs = rsqrtf(var + 1e-5f);
        float* outp = hlng + (size_t)b*HID*NN;
        #pragma unroll
        for(int i=0;i<8;i++){
            int c=g*8+i;
            float v=(acc[i]-mu)*rs*gam[c] + bet[c];
            outp[c*NN + n] = v;
        }
    }
}

// --------------------------------- Fused GRU1+GRU2+FC, 4-way k-split, vector-scalar weights
// 512 threads = 8 waves. Waves 0-3: GRU1; waves 4-7: GRU2. Lane = kq*16+uu.
// Weights are 12 named v4u SSA values (no local arrays -> no alloca/scratch).
__global__ __launch_bounds__(512,1) void k_gruf(
    const float* __restrict__ hlng, const u32* __restrict__ wpk,
    const float* __restrict__ bi1, const float* __restrict__ bh1,
    const float* __restrict__ bi2, const float* __restrict__ bh2,
    const float* __restrict__ Wf, const float* __restrict__ bfv,
    void* __restrict__ outp, const int* __restrict__ flag)
{
    const int b=blockIdx.x, t=threadIdx.x;
    const int wave=t>>6, lane=t&63;
    const int layer=wave>>2;          // 0 = GRU1 waves, 1 = GRU2 waves
    const int uu=lane&15, kq=lane>>4; // unit-within-wave, k-quarter
    const int u=(wave&3)*16+uu;       // hidden unit 0..63

    __shared__ __align__(16) u32 s_x1[64][32];  // GRU1 input fp16, K zero-padded to 64
    __shared__ __align__(16) u32 s_h1[2][32];   // y1/h1 double buffer (64 f16)
    __shared__ __align__(16) u32 s_h2[2][32];   // h2 double buffer
    __shared__ float s_h2f[64];                 // final h2 fp32

    {   const float2* g=(const float2*)(hlng + (size_t)b*2048);
        for(int w=t;w<2048;w+=512){
            int step=w>>5, j=w&31;
            u32 v=0u;
            if(j<16){ float2 f=g[step*16+j]; v=packf16(f.x,f.y); }
            s_x1[step][j]=v;
        }
    }
    if(t<32){ s_h1[0][t]=0u; s_h1[1][t]=0u; s_h2[0][t]=0u; s_h2[1][t]=0u; }

    // weights as named vector scalars (v4u pairs per row-quarter)
    const v4u* wi4 = (const v4u*)(wpk + (size_t)(layer*2+0)*6144);
    const v4u* wh4 = (const v4u*)(wpk + (size_t)(layer*2+1)*6144);
    const int q2 = kq*2;
    v4u wiR0=wi4[(u     )*8+q2], wiR1=wi4[(u     )*8+q2+1];
    v4u wiZ0=wi4[(64+u  )*8+q2], wiZ1=wi4[(64+u  )*8+q2+1];
    v4u wiN0=wi4[(128+u )*8+q2], wiN1=wi4[(128+u )*8+q2+1];
    v4u whR0=wh4[(u     )*8+q2], whR1=wh4[(u     )*8+q2+1];
    v4u whZ0=wh4[(64+u  )*8+q2], whZ1=wh4[(64+u  )*8+q2+1];
    v4u whN0=wh4[(128+u )*8+q2], whN1=wh4[(128+u )*8+q2+1];

    const float* bi = layer? bi2:bi1;
    const float* bh = layer? bh2:bh1;
    float br=bi[u]+bh[u], bz=bi[64+u]+bh[64+u], bxn=bi[128+u], bhn=bh[128+u];

    // pin against sinking/remat (no-op if values are already register-resident)
    asm volatile("" : "+v"(wiR0),"+v"(wiR1),"+v"(wiZ0),"+v"(wiZ1),"+v"(wiN0),"+v"(wiN1),
                      "+v"(whR0),"+v"(whR1),"+v"(whZ0),"+v"(whZ1),"+v"(whN0),"+v"(whN1),
                      "+v"(br),"+v"(bz),"+v"(bxn),"+v"(bhn));

    float h=0.f;
    __syncthreads();

    for(int it=0; it<=64; ++it){
        const int pb=(it-1)&1, cb=it&1;
        const bool act = layer ? (it>=1) : (it<64);
        const int xi = (it<64)? it : 0;
        const v4u* xp = layer ? (const v4u*)&s_h1[pb][kq*8] : (const v4u*)&s_x1[xi][kq*8];
        const v4u* hp = layer ? (const v4u*)&s_h2[pb][kq*8] : (const v4u*)&s_h1[pb][kq*8];
        v4u xa=xp[0], xb=xp[1];
        v4u ha=hp[0], hb=hp[1];
        float pr=0.f,pz=0.f,pxn=0.f,phn=0.f;
        DOT8(pr , xa,xb, wiR0,wiR1);
        DOT8(pz , xa,xb, wiZ0,wiZ1);
        DOT8(pxn, xa,xb, wiN0,wiN1);
        DOT8(pr , ha,hb, whR0,whR1);
        DOT8(pz , ha,hb, whZ0,whZ1);
        DOT8(phn, ha,hb, whN0,whN1);
        // combine 4 k-quarters (all lanes end with full sums)
        pr +=__shfl_xor(pr ,16,64); pz +=__shfl_xor(pz ,16,64);
        pxn+=__shfl_xor(pxn,16,64); phn+=__shfl_xor(phn,16,64);
        pr +=__shfl_xor(pr ,32,64); pz +=__shfl_xor(pz ,32,64);
        pxn+=__shfl_xor(pxn,32,64); phn+=__shfl_xor(phn,32,64);
        float r=sigm(pr+br), z=sigm(pz+bz);
        float n=tanh_(pxn+bxn + r*(phn+bhn));
        float hn=(1.f-z)*n + z*h;
        h = act ? hn : h;
        if(act && kq==0){
            u16 hv=f2h16(h);
            if(layer==0) ((u16*)s_h1[cb])[u]=hv;
            else { ((u16*)s_h2[cb])[u]=hv; if(it==64) s_h2f[u]=h; }
        }
        __syncthreads();
    }

    if(t<OUT_CH){
        float acc=bfv[t];
        const float4* wp=(const float4*)(Wf + t*64);
        const float4* hp=(const float4*)s_h2f;
        #pragma unroll
        for(int k=0;k<16;k++){
            float4 w=wp[k], v=hp[k];
            acc += w.x*v.x + w.y*v.y + w.z*v.z + w.w*v.w;
        }
        if(*flag) ((float*)outp)[b*OUT_CH+t]=acc;
        else      ((u16*)outp)[b*OUT_CH+t]=f2bf(acc);
    }
}

extern "C" void kernel_launch(void* const* d_in, const int* in_sizes, int n_in,
                              void* d_out, int out_size, void* d_ws, size_t ws_size,
                              hipStream_t stream)
{
    char* ws=(char*)d_ws;
    int* flag = (int*)ws;
    float* cf = (float*)(ws + 256);
    float* c_x   = cf; cf+=196608;
    float* c_W1  = cf; cf+=6144;
    float* c_as1 = cf; cf+=512;
    float* c_ad1 = cf; cf+=512;
    float* c_b1  = cf; cf+=512;
    float* c_as2 = cf; cf+=64;
    float* c_ad2 = cf; cf+=64;
    float* c_b2  = cf; cf+=64;
    float* c_gam = cf; cf+=64;
    float* c_bet = cf; cf+=64;
    float* c_bi1 = cf; cf+=192;
    float* c_bh1 = cf; cf+=192;
    float* c_bi2 = cf; cf+=192;
    float* c_bh2 = cf; cf+=192;
    float* c_Wf  = cf; cf+=576;
    float* c_bf  = cf; cf+=9;
    uintptr_t p = ((uintptr_t)cf + 255) & ~(uintptr_t)255;
    u16* c_W2i = (u16*)p;                        // 32768 f16 = 64 KB (interleaved)
    p = (p + 32768*2 + 255) & ~(uintptr_t)255;
    u32* wpk = (u32*)p;                          // 4*192*32 u32 = 96 KB (packed GRU weights)
    p = (p + 24576*4 + 255) & ~(uintptr_t)255;
    u32* h1g = (u32*)p;                          // 512*32*256 u32 = 16.78 MB (fp16-packed)
    p = (p + (size_t)BATCH*NN*256*4 + 255) & ~(uintptr_t)255;
    float* hlng = (float*)p;                     // 512*64*32 f32 = 4.19 MB

    const int* ei = (const int*)d_in[1];

    CvtDesc d;
    const int srcIdx[16] = {0,2,3,4,5,7,8,9,10,11,14,15,18,19,20,21};
    void* dsts[16] = {c_x,c_W1,c_as1,c_ad1,c_b1,c_as2,c_ad2,c_b2,c_gam,c_bet,
                      c_bi1,c_bh1,c_bi2,c_bh2,c_Wf,c_bf};
    const int ns[16] = {196608,6144,512,512,512,64,64,64,64,64,
                        192,192,192,192,576,9};
    for(int i=0;i<16;i++){ d.src[i]=d_in[srcIdx[i]]; d.dst[i]=dsts[i]; d.n[i]=ns[i]; }

    k_detect <<<dim3(1),dim3(256),0,stream>>>((const u32*)d_in[0], flag);
    k_convert<<<dim3(16,8),dim3(256),0,stream>>>(d, flag);
    k_w2i    <<<dim3(128),dim3(256),0,stream>>>(d_in[6], c_W2i, flag);
    k_wpk    <<<dim3(96),dim3(256),0,stream>>>(d_in[12],d_in[13],d_in[16],d_in[17], wpk, flag);
    k_gat1   <<<dim3(BATCH),dim3(256),0,stream>>>(c_x,ei,c_W1,c_as1,c_ad1,c_b1,h1g);
    k_gat2ln <<<dim3(BATCH),dim3(256),0,stream>>>(h1g,ei,(const uint4*)c_W2i,c_as2,c_ad2,c_b2,c_gam,c_bet,hlng);
    k_gruf   <<<dim3(BATCH),dim3(512),0,stream>>>(hlng,wpk,c_bi1,c_bh1,c_bi2,c_bh2,c_Wf,c_bf,d_out,flag);
}